// Round 3
// baseline (274.953 us; speedup 1.0000x reference)
//
#include <hip/hip_runtime.h>
#include <math.h>

#define B_ 8
#define C_ 64
#define K_ 32
#define HW_ 16384
#define CHUNK_ 128
#define NCHUNKOUT_ 64        // 64 partial slabs, 2 chunks accumulated per block
#define LD1 68               // padded LDS row stride (floats)
#define NEG_SLOPE_ 0.1f

// ws layout:
//   [0, 8MB)          float partial[B_][NCHUNKOUT_][C_][C_]
//   [8MB, 8MB+256KB)  float tab2[B_][128][C_]   rows 0..63 = w[d][c], rows 64..127 = bias[d][c]

__global__ __launch_bounds__(256) void corr_partial_kernel(
    const float* __restrict__ LR, const float* __restrict__ HR,
    float* __restrict__ partial)
{
    __shared__ float lrS[CHUNK_][LD1];
    __shared__ float hrS[CHUNK_][LD1];
    const int blk = blockIdx.x;
    const int b = blk >> 6;            // / 64
    const int j = blk & 63;
    const int t = threadIdx.x;

    const int cq = t >> 4;
    const int dq = t & 15;
    const int c0 = cq * 4, d0 = dq * 4;
    float acc[4][4] = {};

    for (int half = 0; half < 2; ++half) {
        const int n0 = (j * 2 + half) * CHUNK_;
        if (half) __syncthreads();     // protect LDS before restage
        for (int i = t; i < C_ * CHUNK_; i += 256) {
            const int c = i / CHUNK_;
            const int n = i % CHUNK_;
            lrS[n][c] = LR[(size_t)(b * C_ + c) * HW_ + n0 + n];
            hrS[n][c] = HR[(size_t)(b * C_ + c) * HW_ + n0 + n];
        }
        __syncthreads();

        for (int n = 0; n < CHUNK_; ++n) {
            const float4 lv = *reinterpret_cast<const float4*>(&lrS[n][c0]);
            const float4 hv = *reinterpret_cast<const float4*>(&hrS[n][d0]);
            const float l[4] = {lv.x, lv.y, lv.z, lv.w};
            const float h[4] = {hv.x, hv.y, hv.z, hv.w};
            #pragma unroll
            for (int i = 0; i < 4; ++i)
                #pragma unroll
                for (int k = 0; k < 4; ++k)
                    acc[i][k] = fmaf(l[i], h[k], acc[i][k]);
        }
    }

    float* P = partial + (size_t)(b * NCHUNKOUT_ + j) * (C_ * C_);
    #pragma unroll
    for (int i = 0; i < 4; ++i) {
        const float4 v = make_float4(acc[i][0], acc[i][1], acc[i][2], acc[i][3]);
        *reinterpret_cast<float4*>(&P[(c0 + i) * C_ + d0]) = v;
    }
}

// Reduce partials (f64, deterministic), rank channels per (b,c) like lax.top_k
// (stable descending), emit dense weight/bias tables in [b][d][c] layout.
__global__ __launch_bounds__(64) void rank_kernel(
    const float* __restrict__ partial, const float* __restrict__ w1,
    float* __restrict__ tab2)
{
    __shared__ double vals[C_];
    const int blk = blockIdx.x;     // b*64 + c
    const int b = blk >> 6;
    const int c = blk & 63;
    const int d = threadIdx.x;

    double acc = 0.0;
    for (int k = 0; k < NCHUNKOUT_; ++k)
        acc += (double)partial[(size_t)(b * NCHUNKOUT_ + k) * (C_ * C_) + c * C_ + d];
    vals[d] = acc;
    __syncthreads();

    int r = 0;
    for (int jj = 0; jj < C_; ++jj) {
        const double vj = vals[jj];
        r += (int)((vj > acc) || (vj == acc && jj < d));   // stable descending rank
    }

    float wv = 0.f, bv = -1e30f;
    if (r < K_) { wv = w1[r + 1]; bv = 0.f; }
    tab2[(size_t)b * 128 * C_ + d * C_ + c] = wv;
    tab2[(size_t)b * 128 * C_ + (64 + d) * C_ + c] = bv;
}

// c-per-lane dense fusion: lane = LR channel, tables register-resident,
// HR delivered as lane-uniform (broadcast) float4 loads. Pure-VALU inner loop.
__global__ __launch_bounds__(256, 3) void fusion_lane_kernel(
    const float* __restrict__ HR, const float* __restrict__ LR,
    const float* __restrict__ tab2,
    const float* __restrict__ w1, const float* __restrict__ b1,
    const float* __restrict__ w2, const float* __restrict__ b2,
    float* __restrict__ out)
{
    const int t = threadIdx.x;
    const int lane = t & 63;          // c
    const int wv = t >> 6;
    const int bid = blockIdx.x;
    const int b = bid >> 7;           // 128 px-blocks per batch
    const int pxb = bid & 127;
    const int px0w = pxb * 128 + wv * 32;

    // preload this channel's dense weight/bias rows (coalesced over lanes)
    const float* T = tab2 + (size_t)b * 128 * C_ + lane;
    float w[64], bs[64];
    #pragma unroll
    for (int d = 0; d < 64; ++d) {
        w[d]  = T[(size_t)d * C_];
        bs[d] = T[(size_t)(64 + d) * C_];
    }

    const float w10 = w1[0];
    const float b1v = b1[0], w2v = w2[0], b2v = b2[0];
    const float* HRb = HR + (size_t)b * C_ * HW_;
    const float* LRb = LR + (size_t)(b * C_ + lane) * HW_;
    float* outb = out + (size_t)(b * C_ + lane) * HW_;

    #pragma unroll 1
    for (int tile = 0; tile < 4; ++tile) {
        const int px0 = px0w + tile * 8;
        float acc[8] = {0.f, 0.f, 0.f, 0.f, 0.f, 0.f, 0.f, 0.f};
        float mx[8]  = {-1e30f, -1e30f, -1e30f, -1e30f,
                        -1e30f, -1e30f, -1e30f, -1e30f};
        #pragma unroll
        for (int d = 0; d < 64; ++d) {
            const float4 h0 = *reinterpret_cast<const float4*>(&HRb[(size_t)d * HW_ + px0]);
            const float4 h1 = *reinterpret_cast<const float4*>(&HRb[(size_t)d * HW_ + px0 + 4]);
            const float h[8] = {h0.x, h0.y, h0.z, h0.w, h1.x, h1.y, h1.z, h1.w};
            #pragma unroll
            for (int p = 0; p < 8; ++p) {
                acc[p] = fmaf(h[p], w[d], acc[p]);
                mx[p] = fmaxf(mx[p], h[p] + bs[d]);
            }
        }

        const float4 l0 = *reinterpret_cast<const float4*>(&LRb[px0]);
        const float4 l1 = *reinterpret_cast<const float4*>(&LRb[px0 + 4]);
        const float l[8] = {l0.x, l0.y, l0.z, l0.w, l1.x, l1.y, l1.z, l1.w};
        float o[8];
        #pragma unroll
        for (int p = 0; p < 8; ++p) {
            float f = fmaf(w10, l[p], acc[p]) + b1v;
            f = f >= 0.f ? f : NEG_SLOPE_ * f;
            f = fmaf(w2v, f, b2v);
            const float s = 1.f / (1.f + __expf(-mx[p]));
            o[p] = f * (1.f + s);
        }
        *reinterpret_cast<float4*>(&outb[px0]) =
            make_float4(o[0], o[1], o[2], o[3]);
        *reinterpret_cast<float4*>(&outb[px0 + 4]) =
            make_float4(o[4], o[5], o[6], o[7]);
    }
}

extern "C" void kernel_launch(void* const* d_in, const int* in_sizes, int n_in,
                              void* d_out, int out_size, void* d_ws, size_t ws_size,
                              hipStream_t stream)
{
    const float* HR = (const float*)d_in[0];
    const float* LR = (const float*)d_in[1];
    const float* w1 = (const float*)d_in[2];
    const float* b1 = (const float*)d_in[3];
    const float* w2 = (const float*)d_in[4];
    const float* b2 = (const float*)d_in[5];
    float* out = (float*)d_out;

    float* partial = (float*)d_ws;
    float* tab2 = (float*)((char*)d_ws + (size_t)B_ * NCHUNKOUT_ * C_ * C_ * sizeof(float));

    corr_partial_kernel<<<B_ * NCHUNKOUT_, 256, 0, stream>>>(LR, HR, partial);
    rank_kernel<<<B_ * C_, 64, 0, stream>>>(partial, w1, tab2);
    fusion_lane_kernel<<<B_ * 128, 256, 0, stream>>>(HR, LR, tab2, w1, b1, w2, b2, out);
}

// Round 4
// 114.982 us; speedup vs baseline: 2.3913x; 2.3913x over previous
//
#include <hip/hip_runtime.h>
#include <math.h>

#define B_ 8
#define C_ 64
#define K_ 32
#define HW_ 16384
#define CHUNK_ 128
#define NCHUNKOUT_ 64        // 64 partial slabs, 2 chunks accumulated per block
#define LD1 68               // padded LDS row stride (floats)
#define NEG_SLOPE_ 0.1f

// ws layout:
//   [0, 8MB)          float  partial[B_][NCHUNKOUT_][C_][C_]
//   [8MB, 8MB+256KB)  float2 tabI[B_][64 d][64 c]  = (w, bias)

__global__ __launch_bounds__(256) void corr_partial_kernel(
    const float* __restrict__ LR, const float* __restrict__ HR,
    float* __restrict__ partial)
{
    __shared__ float lrS[CHUNK_][LD1];
    __shared__ float hrS[CHUNK_][LD1];
    const int blk = blockIdx.x;
    const int b = blk >> 6;            // / 64
    const int j = blk & 63;
    const int t = threadIdx.x;

    const int cq = t >> 4;
    const int dq = t & 15;
    const int c0 = cq * 4, d0 = dq * 4;
    float acc[4][4] = {};

    for (int half = 0; half < 2; ++half) {
        const int n0 = (j * 2 + half) * CHUNK_;
        if (half) __syncthreads();     // protect LDS before restage
        for (int i = t; i < C_ * CHUNK_; i += 256) {
            const int c = i / CHUNK_;
            const int n = i % CHUNK_;
            lrS[n][c] = LR[(size_t)(b * C_ + c) * HW_ + n0 + n];
            hrS[n][c] = HR[(size_t)(b * C_ + c) * HW_ + n0 + n];
        }
        __syncthreads();

        for (int n = 0; n < CHUNK_; ++n) {
            const float4 lv = *reinterpret_cast<const float4*>(&lrS[n][c0]);
            const float4 hv = *reinterpret_cast<const float4*>(&hrS[n][d0]);
            const float l[4] = {lv.x, lv.y, lv.z, lv.w};
            const float h[4] = {hv.x, hv.y, hv.z, hv.w};
            #pragma unroll
            for (int i = 0; i < 4; ++i)
                #pragma unroll
                for (int k = 0; k < 4; ++k)
                    acc[i][k] = fmaf(l[i], h[k], acc[i][k]);
        }
    }

    float* P = partial + (size_t)(b * NCHUNKOUT_ + j) * (C_ * C_);
    #pragma unroll
    for (int i = 0; i < 4; ++i) {
        const float4 v = make_float4(acc[i][0], acc[i][1], acc[i][2], acc[i][3]);
        *reinterpret_cast<float4*>(&P[(c0 + i) * C_ + d0]) = v;
    }
}

// Reduce partials (f64, deterministic), rank channels per (b,c) like lax.top_k
// (stable descending), emit interleaved (w,bias) table in [b][d][c] layout.
__global__ __launch_bounds__(64) void rank_kernel(
    const float* __restrict__ partial, const float* __restrict__ w1,
    float2* __restrict__ tabI)
{
    __shared__ double vals[C_];
    const int blk = blockIdx.x;     // b*64 + c
    const int b = blk >> 6;
    const int c = blk & 63;
    const int d = threadIdx.x;

    double acc = 0.0;
    for (int k = 0; k < NCHUNKOUT_; ++k)
        acc += (double)partial[(size_t)(b * NCHUNKOUT_ + k) * (C_ * C_) + c * C_ + d];
    vals[d] = acc;
    __syncthreads();

    int r = 0;
    for (int jj = 0; jj < C_; ++jj) {
        const double vj = vals[jj];
        r += (int)((vj > acc) || (vj == acc && jj < d));   // stable descending rank
    }

    float wv = 0.f, bv = -1e30f;
    if (r < K_) { wv = w1[r + 1]; bv = 0.f; }
    tabI[(size_t)b * 4096 + d * 64 + c] = make_float2(wv, bv);
}

// c-per-lane dense fusion: lane = LR channel. (w,bias) table lives in LDS
// (32 KB, staged once per block); HR delivered as wave-uniform broadcast
// float4 loads. Inner loop: 1 ds_read_b64 + 2 VMEM + 24 VALU per d.
__global__ __launch_bounds__(256, 4) void fusion_lds_kernel(
    const float* __restrict__ HR, const float* __restrict__ LR,
    const float2* __restrict__ tabI,
    const float* __restrict__ w1, const float* __restrict__ b1,
    const float* __restrict__ w2, const float* __restrict__ b2,
    float* __restrict__ out)
{
    __shared__ float2 T[64][64];      // [d][c], 32 KB

    const int t = threadIdx.x;
    const int bid = blockIdx.x;
    const int b = bid >> 7;           // 128 px-blocks per batch
    const int pxb = bid & 127;

    // stage table: 8192 floats = 2048 float4
    {
        const float4* src = reinterpret_cast<const float4*>(tabI + (size_t)b * 4096);
        float4* dst = reinterpret_cast<float4*>(&T[0][0]);
        #pragma unroll
        for (int i = 0; i < 8; ++i)
            dst[t + i * 256] = src[t + i * 256];
    }
    __syncthreads();

    const int lane = t & 63;          // c
    const int wv = t >> 6;
    const int px0w = pxb * 128 + wv * 32;

    const float w10 = w1[0];
    const float b1v = b1[0], w2v = w2[0], b2v = b2[0];
    const float* HRb = HR + (size_t)b * C_ * HW_;
    const float* LRb = LR + (size_t)(b * C_ + lane) * HW_;
    float* outb = out + (size_t)(b * C_ + lane) * HW_;

    #pragma unroll 1
    for (int tile = 0; tile < 4; ++tile) {
        const int px0 = px0w + tile * 8;
        float acc[8] = {0.f, 0.f, 0.f, 0.f, 0.f, 0.f, 0.f, 0.f};
        float mx[8]  = {-1e30f, -1e30f, -1e30f, -1e30f,
                        -1e30f, -1e30f, -1e30f, -1e30f};
        #pragma unroll 16
        for (int d = 0; d < 64; ++d) {
            const float4 h0 = *reinterpret_cast<const float4*>(&HRb[(size_t)d * HW_ + px0]);
            const float4 h1 = *reinterpret_cast<const float4*>(&HRb[(size_t)d * HW_ + px0 + 4]);
            const float2 wb = T[d][lane];
            const float h[8] = {h0.x, h0.y, h0.z, h0.w, h1.x, h1.y, h1.z, h1.w};
            #pragma unroll
            for (int p = 0; p < 8; ++p) {
                acc[p] = fmaf(h[p], wb.x, acc[p]);
                mx[p] = fmaxf(mx[p], h[p] + wb.y);
            }
        }

        const float4 l0 = *reinterpret_cast<const float4*>(&LRb[px0]);
        const float4 l1 = *reinterpret_cast<const float4*>(&LRb[px0 + 4]);
        const float l[8] = {l0.x, l0.y, l0.z, l0.w, l1.x, l1.y, l1.z, l1.w};
        float o[8];
        #pragma unroll
        for (int p = 0; p < 8; ++p) {
            float f = fmaf(w10, l[p], acc[p]) + b1v;
            f = f >= 0.f ? f : NEG_SLOPE_ * f;
            f = fmaf(w2v, f, b2v);
            const float s = 1.f / (1.f + __expf(-mx[p]));
            o[p] = f * (1.f + s);
        }
        *reinterpret_cast<float4*>(&outb[px0]) =
            make_float4(o[0], o[1], o[2], o[3]);
        *reinterpret_cast<float4*>(&outb[px0 + 4]) =
            make_float4(o[4], o[5], o[6], o[7]);
    }
}

extern "C" void kernel_launch(void* const* d_in, const int* in_sizes, int n_in,
                              void* d_out, int out_size, void* d_ws, size_t ws_size,
                              hipStream_t stream)
{
    const float* HR = (const float*)d_in[0];
    const float* LR = (const float*)d_in[1];
    const float* w1 = (const float*)d_in[2];
    const float* b1 = (const float*)d_in[3];
    const float* w2 = (const float*)d_in[4];
    const float* b2 = (const float*)d_in[5];
    float* out = (float*)d_out;

    float* partial = (float*)d_ws;
    float2* tabI = (float2*)((char*)d_ws + (size_t)B_ * NCHUNKOUT_ * C_ * C_ * sizeof(float));

    corr_partial_kernel<<<B_ * NCHUNKOUT_, 256, 0, stream>>>(LR, HR, partial);
    rank_kernel<<<B_ * C_, 64, 0, stream>>>(partial, w1, tabI);
    fusion_lds_kernel<<<B_ * 128, 256, 0, stream>>>(HR, LR, tabI, w1, b1, w2, b2, out);
}

// Round 5
// 78.791 us; speedup vs baseline: 3.4897x; 1.4593x over previous
//
#include <hip/hip_runtime.h>
#include <math.h>

#define B_ 8
#define C_ 64
#define K_ 32
#define HW_ 16384
#define CHUNK_ 128
#define NCHUNKOUT_ 64        // 64 partial slabs, 2 chunks accumulated per block
#define LDN 132              // padded [c][n] row stride (floats): 16B-aligned, +4 banks/row
#define TILE_ 256            // fusion px tile
#define NEG_SLOPE_ 0.1f

// ws layout:
//   [0, 8MB)          float partial[B_][NCHUNKOUT_][C_][C_]
//   [8MB, 8MB+64KB)   int   idxb[B_][C_][K_]

__global__ __launch_bounds__(256, 2) void corr_partial_kernel(
    const float* __restrict__ LR, const float* __restrict__ HR,
    float* __restrict__ partial)
{
    __shared__ float lrS[C_][LDN];   // [c][n] layout, b128-stageable
    __shared__ float hrS[C_][LDN];
    const int blk = blockIdx.x;
    const int b = blk >> 6;
    const int j = blk & 63;
    const int t = threadIdx.x;

    const int cq = t >> 4;           // 0..15
    const int dq = t & 15;           // 0..15
    float acc[4][4] = {};

    for (int half = 0; half < 2; ++half) {
        const int n0 = (j * 2 + half) * CHUNK_;
        if (half) __syncthreads();
        // stage: per array 2048 float4; thread does 8 each; coalesced global
        // float4 -> contiguous ds_write_b128 (conflict-free)
        #pragma unroll
        for (int p = 0; p < 8; ++p) {
            const int f = p * 256 + t;
            const int c = f >> 5;
            const int q = f & 31;
            *reinterpret_cast<float4*>(&lrS[c][q * 4]) =
                *reinterpret_cast<const float4*>(&LR[(size_t)(b * C_ + c) * HW_ + n0 + q * 4]);
            *reinterpret_cast<float4*>(&hrS[c][q * 4]) =
                *reinterpret_cast<const float4*>(&HR[(size_t)(b * C_ + c) * HW_ + n0 + q * 4]);
        }
        __syncthreads();

        // thread tile: c-rows cq+16i, d-rows dq+16j (lane-adjacent rows -> +4 banks)
        for (int nq = 0; nq < 32; ++nq) {
            float4 lv[4], hv[4];
            #pragma unroll
            for (int i = 0; i < 4; ++i)
                lv[i] = *reinterpret_cast<const float4*>(&lrS[cq + 16 * i][nq * 4]);
            #pragma unroll
            for (int jj = 0; jj < 4; ++jj)
                hv[jj] = *reinterpret_cast<const float4*>(&hrS[dq + 16 * jj][nq * 4]);
            #pragma unroll
            for (int i = 0; i < 4; ++i) {
                const float l[4] = {lv[i].x, lv[i].y, lv[i].z, lv[i].w};
                #pragma unroll
                for (int jj = 0; jj < 4; ++jj) {
                    const float h[4] = {hv[jj].x, hv[jj].y, hv[jj].z, hv[jj].w};
                    acc[i][jj] = fmaf(l[0], h[0], acc[i][jj]);
                    acc[i][jj] = fmaf(l[1], h[1], acc[i][jj]);
                    acc[i][jj] = fmaf(l[2], h[2], acc[i][jj]);
                    acc[i][jj] = fmaf(l[3], h[3], acc[i][jj]);
                }
            }
        }
    }

    float* P = partial + (size_t)(b * NCHUNKOUT_ + j) * (C_ * C_);
    #pragma unroll
    for (int i = 0; i < 4; ++i)
        #pragma unroll
        for (int jj = 0; jj < 4; ++jj)
            P[(cq + 16 * i) * C_ + (dq + 16 * jj)] = acc[i][jj];
}

// Reduce partials (f64, deterministic), rank channels per (b,c) like lax.top_k
// (stable descending), emit top-K channel indices.
__global__ __launch_bounds__(64) void rank_kernel(
    const float* __restrict__ partial, int* __restrict__ idxb)
{
    __shared__ double vals[C_];
    const int blk = blockIdx.x;     // b*64 + c
    const int b = blk >> 6;
    const int c = blk & 63;
    const int d = threadIdx.x;

    double acc = 0.0;
    for (int k = 0; k < NCHUNKOUT_; ++k)
        acc += (double)partial[(size_t)(b * NCHUNKOUT_ + k) * (C_ * C_) + c * C_ + d];
    vals[d] = acc;
    __syncthreads();

    int r = 0;
    for (int jj = 0; jj < C_; ++jj) {
        const double vj = vals[jj];
        r += (int)((vj > acc) || (vj == acc && jj < d));   // stable descending rank
    }
    if (r < K_) idxb[blk * K_ + r] = d;
}

// Gather fusion: stage HR[64][256] px-slab in LDS; per LR channel c do 32
// conflict-free ds_read_b32 gathers (idx/w1 via uniform scalar loads).
__global__ __launch_bounds__(256, 2) void fusion_gather_kernel(
    const float* __restrict__ HR, const float* __restrict__ LR,
    const int* __restrict__ idxb,
    const float* __restrict__ w1, const float* __restrict__ b1,
    const float* __restrict__ w2, const float* __restrict__ b2,
    float* __restrict__ out)
{
    __shared__ float hrS[C_][TILE_];   // 64 KB

    const int t = threadIdx.x;
    const int bid = blockIdx.x;        // 512 = B * (HW/TILE)
    const int b = bid >> 6;
    const int px0 = (bid & 63) * TILE_;

    const float* HRb = HR + (size_t)b * C_ * HW_;
    #pragma unroll
    for (int i = 0; i < 16; ++i) {
        const int f = i * 256 + t;
        const int c = f >> 6;
        const int q = f & 63;
        *reinterpret_cast<float4*>(&hrS[c][q * 4]) =
            *reinterpret_cast<const float4*>(&HRb[(size_t)c * HW_ + px0 + q * 4]);
    }
    __syncthreads();

    const int* idxc = idxb + b * C_ * K_;
    const float w10 = w1[0];
    const float b1v = b1[0], w2v = w2[0], b2v = b2[0];

    for (int c = 0; c < C_; ++c) {
        const float lrv = LR[(size_t)(b * C_ + c) * HW_ + px0 + t];  // issue early
        float acc = 0.f, mx = -1e30f;
        #pragma unroll
        for (int k = 0; k < K_; ++k) {
            const int d = idxc[c * K_ + k];      // uniform -> s_load
            const float h = hrS[d][t];           // lanes consecutive -> conflict-free
            acc = fmaf(h, w1[k + 1], acc);       // w1[k+1] uniform -> SGPR
            mx = fmaxf(mx, h);
        }
        float f = fmaf(w10, lrv, acc) + b1v;
        f = f >= 0.f ? f : NEG_SLOPE_ * f;
        f = fmaf(w2v, f, b2v);
        const float s = 1.f / (1.f + __expf(-mx));
        out[(size_t)(b * C_ + c) * HW_ + px0 + t] = f * (1.f + s);
    }
}

extern "C" void kernel_launch(void* const* d_in, const int* in_sizes, int n_in,
                              void* d_out, int out_size, void* d_ws, size_t ws_size,
                              hipStream_t stream)
{
    const float* HR = (const float*)d_in[0];
    const float* LR = (const float*)d_in[1];
    const float* w1 = (const float*)d_in[2];
    const float* b1 = (const float*)d_in[3];
    const float* w2 = (const float*)d_in[4];
    const float* b2 = (const float*)d_in[5];
    float* out = (float*)d_out;

    float* partial = (float*)d_ws;
    int* idxb = (int*)((char*)d_ws + (size_t)B_ * NCHUNKOUT_ * C_ * C_ * sizeof(float));

    corr_partial_kernel<<<B_ * NCHUNKOUT_, 256, 0, stream>>>(LR, HR, partial);
    rank_kernel<<<B_ * C_, 64, 0, stream>>>(partial, idxb);
    fusion_gather_kernel<<<B_ * (HW_ / TILE_), 256, 0, stream>>>(HR, LR, idxb, w1, b1, w2, b2, out);
}

// Round 6
// 59.794 us; speedup vs baseline: 4.5984x; 1.3177x over previous
//
#include <hip/hip_runtime.h>
#include <math.h>

#define B_ 8
#define C_ 64
#define K_ 32
#define HW_ 16384
#define CHUNK_ 128
#define NCHUNKOUT_ 64        // 64 partial slabs, 2 chunks accumulated per block
#define LDN 132              // padded [c][n] row stride (floats): 16B-aligned, +4 banks/row
#define TILE_ 256            // fusion px tile
#define NEG_SLOPE_ 0.1f

// ws layout:
//   [0, 8MB)          float partial[B_][NCHUNKOUT_][C_][C_]
//   [8MB, 8MB+64KB)   int   idxb[B_][C_][K_]

__global__ __launch_bounds__(256, 2) void corr_partial_kernel(
    const float* __restrict__ LR, const float* __restrict__ HR,
    float* __restrict__ partial)
{
    __shared__ float lrS[C_][LDN];   // [c][n] layout, b128-stageable
    __shared__ float hrS[C_][LDN];
    const int blk = blockIdx.x;
    const int b = blk >> 6;
    const int j = blk & 63;
    const int t = threadIdx.x;

    const int cq = t >> 4;           // 0..15
    const int dq = t & 15;           // 0..15
    float acc[4][4] = {};

    for (int half = 0; half < 2; ++half) {
        const int n0 = (j * 2 + half) * CHUNK_;
        if (half) __syncthreads();
        // stage: per array 2048 float4; thread does 8 each; coalesced global
        // float4 -> contiguous ds_write_b128 (conflict-free)
        #pragma unroll
        for (int p = 0; p < 8; ++p) {
            const int f = p * 256 + t;
            const int c = f >> 5;
            const int q = f & 31;
            *reinterpret_cast<float4*>(&lrS[c][q * 4]) =
                *reinterpret_cast<const float4*>(&LR[(size_t)(b * C_ + c) * HW_ + n0 + q * 4]);
            *reinterpret_cast<float4*>(&hrS[c][q * 4]) =
                *reinterpret_cast<const float4*>(&HR[(size_t)(b * C_ + c) * HW_ + n0 + q * 4]);
        }
        __syncthreads();

        // thread tile: c-rows cq+16i, d-rows dq+16j (lane-adjacent rows -> +4 banks)
        for (int nq = 0; nq < 32; ++nq) {
            float4 lv[4], hv[4];
            #pragma unroll
            for (int i = 0; i < 4; ++i)
                lv[i] = *reinterpret_cast<const float4*>(&lrS[cq + 16 * i][nq * 4]);
            #pragma unroll
            for (int jj = 0; jj < 4; ++jj)
                hv[jj] = *reinterpret_cast<const float4*>(&hrS[dq + 16 * jj][nq * 4]);
            #pragma unroll
            for (int i = 0; i < 4; ++i) {
                const float l[4] = {lv[i].x, lv[i].y, lv[i].z, lv[i].w};
                #pragma unroll
                for (int jj = 0; jj < 4; ++jj) {
                    const float h[4] = {hv[jj].x, hv[jj].y, hv[jj].z, hv[jj].w};
                    acc[i][jj] = fmaf(l[0], h[0], acc[i][jj]);
                    acc[i][jj] = fmaf(l[1], h[1], acc[i][jj]);
                    acc[i][jj] = fmaf(l[2], h[2], acc[i][jj]);
                    acc[i][jj] = fmaf(l[3], h[3], acc[i][jj]);
                }
            }
        }
    }

    float* P = partial + (size_t)(b * NCHUNKOUT_ + j) * (C_ * C_);
    #pragma unroll
    for (int i = 0; i < 4; ++i)
        #pragma unroll
        for (int jj = 0; jj < 4; ++jj)
            P[(cq + 16 * i) * C_ + (dq + 16 * jj)] = acc[i][jj];
}

// Reduce partials (f64, deterministic), rank channels per (b,c) like lax.top_k
// (stable descending), emit top-K channel indices.
__global__ __launch_bounds__(64) void rank_kernel(
    const float* __restrict__ partial, int* __restrict__ idxb)
{
    __shared__ double vals[C_];
    const int blk = blockIdx.x;     // b*64 + c
    const int b = blk >> 6;
    const int c = blk & 63;
    const int d = threadIdx.x;

    double acc = 0.0;
    for (int k = 0; k < NCHUNKOUT_; ++k)
        acc += (double)partial[(size_t)(b * NCHUNKOUT_ + k) * (C_ * C_) + c * C_ + d];
    vals[d] = acc;
    __syncthreads();

    int r = 0;
    for (int jj = 0; jj < C_; ++jj) {
        const double vj = vals[jj];
        r += (int)((vj > acc) || (vj == acc && jj < d));   // stable descending rank
    }
    if (r < K_) idxb[blk * K_ + r] = d;
}

// Gather fusion v2: stage HR[64][256] px-slab in LDS; each wave owns a
// c-quarter and all 256 px (float4/lane). Gather is ds_read_b128:
// 1 KB/wave-instr, contiguous -> conflict-free, 4x fewer LDS instrs than b32.
__global__ __launch_bounds__(256, 2) void fusion_gather_kernel(
    const float* __restrict__ HR, const float* __restrict__ LR,
    const int* __restrict__ idxb,
    const float* __restrict__ w1, const float* __restrict__ b1,
    const float* __restrict__ w2, const float* __restrict__ b2,
    float* __restrict__ out)
{
    __shared__ float hrS[C_][TILE_];   // 64 KB

    const int t = threadIdx.x;
    const int bid = blockIdx.x;        // 512 = B * (HW/TILE)
    const int b = bid >> 6;
    const int px0 = (bid & 63) * TILE_;

    const float* HRb = HR + (size_t)b * C_ * HW_;
    #pragma unroll
    for (int i = 0; i < 16; ++i) {
        const int f = i * 256 + t;
        const int c = f >> 6;
        const int q = f & 63;
        *reinterpret_cast<float4*>(&hrS[c][q * 4]) =
            *reinterpret_cast<const float4*>(&HRb[(size_t)c * HW_ + px0 + q * 4]);
    }
    __syncthreads();

    const int wv = t >> 6;             // wave id -> c-quarter
    const int lane = t & 63;
    const int p4 = lane * 4;           // this lane's 4 px within the tile

    const int* idxc = idxb + b * C_ * K_;
    const float w10 = w1[0];
    const float b1v = b1[0], w2v = w2[0], b2v = b2[0];

    #pragma unroll 1
    for (int ci = 0; ci < 16; ++ci) {
        const int c = wv * 16 + ci;
        const float4 l4 = *reinterpret_cast<const float4*>(
            &LR[(size_t)(b * C_ + c) * HW_ + px0 + p4]);         // issue early
        float acc[4] = {0.f, 0.f, 0.f, 0.f};
        float mx[4]  = {-1e30f, -1e30f, -1e30f, -1e30f};
        #pragma unroll
        for (int k = 0; k < K_; ++k) {
            const int d = idxc[c * K_ + k];          // uniform -> s_load
            const float4 h = *reinterpret_cast<const float4*>(&hrS[d][p4]);
            const float wk = w1[k + 1];              // uniform -> SGPR
            acc[0] = fmaf(h.x, wk, acc[0]);
            acc[1] = fmaf(h.y, wk, acc[1]);
            acc[2] = fmaf(h.z, wk, acc[2]);
            acc[3] = fmaf(h.w, wk, acc[3]);
            mx[0] = fmaxf(mx[0], h.x);
            mx[1] = fmaxf(mx[1], h.y);
            mx[2] = fmaxf(mx[2], h.z);
            mx[3] = fmaxf(mx[3], h.w);
        }
        const float l[4] = {l4.x, l4.y, l4.z, l4.w};
        float o[4];
        #pragma unroll
        for (int p = 0; p < 4; ++p) {
            float f = fmaf(w10, l[p], acc[p]) + b1v;
            f = f >= 0.f ? f : NEG_SLOPE_ * f;
            f = fmaf(w2v, f, b2v);
            const float s = 1.f / (1.f + __expf(-mx[p]));
            o[p] = f * (1.f + s);
        }
        *reinterpret_cast<float4*>(&out[(size_t)(b * C_ + c) * HW_ + px0 + p4]) =
            make_float4(o[0], o[1], o[2], o[3]);
    }
}

extern "C" void kernel_launch(void* const* d_in, const int* in_sizes, int n_in,
                              void* d_out, int out_size, void* d_ws, size_t ws_size,
                              hipStream_t stream)
{
    const float* HR = (const float*)d_in[0];
    const float* LR = (const float*)d_in[1];
    const float* w1 = (const float*)d_in[2];
    const float* b1 = (const float*)d_in[3];
    const float* w2 = (const float*)d_in[4];
    const float* b2 = (const float*)d_in[5];
    float* out = (float*)d_out;

    float* partial = (float*)d_ws;
    int* idxb = (int*)((char*)d_ws + (size_t)B_ * NCHUNKOUT_ * C_ * C_ * sizeof(float));

    corr_partial_kernel<<<B_ * NCHUNKOUT_, 256, 0, stream>>>(LR, HR, partial);
    rank_kernel<<<B_ * C_, 64, 0, stream>>>(partial, idxb);
    fusion_gather_kernel<<<B_ * (HW_ / TILE_), 256, 0, stream>>>(HR, LR, idxb, w1, b1, w2, b2, out);
}